// Round 6
// baseline (2077.354 us; speedup 1.0000x reference)
//
#include <hip/hip_runtime.h>
#include <cstdint>

// ---------------------------------------------------------------------------
// GCN Siamese. Class-MAJOR binning -> 8-segment CSR -> interleaved gather agg.
//   col layout: [class0: node0seg node1seg ... | class1: ... | ... class7]
//   A (node,class) segment is written only by blocks with blockIdx&7==class
//   (same XCD under round-robin dispatch) -> write-back lines are XCD-private.
//   per branch:
//     k_bcnt : count per (class, dst node)         [bcnt[cls*N+d], int4 reads]
//     k_deg  : dinv[i] = rsqrt(sum_c bcnt[c*N+i] + 1)
//     k_scanA/B/C: flat exclusive scan of bcnt[8N] -> cur (claim bases)
//     k_bin  : pos = atomicAdd(cur[cls*N+d]); col[pos] = src
//              (after k_bin, cur[x] = segment END; start = end - bcnt[x])
//     k_mm<128>: XWs = bf16(dinv * (X@W1))
//     k_agg<false>: wave/node, 8 class segments interleaved (8-way MLP);
//                   H1 = bf16(relu(di*(acc+XWs[i]) + b1))
//     k_mm<64> : XWs2 = bf16(dinv * (H1@W2))
//     k_agg<true>: same, epilogue pools into emb/cnt (global atomics)
//   head: sigmoid(relu([e1,e2,|e1-e2|]@fc1+b)@fc2+b)
// N=100000, E=3.2M, G=1024
// ---------------------------------------------------------------------------

__device__ __forceinline__ float fatomic(float* p, float v) {
    return unsafeAtomicAdd(p, v);   // hw global_atomic_add_f32
}
__device__ __forceinline__ float bf2f(unsigned short u) {
    union { unsigned int i; float f; } c; c.i = ((unsigned int)u) << 16; return c.f;
}
__device__ __forceinline__ unsigned short f2bf(float f) {
    union { float f; unsigned int i; } c; c.f = f;
    const unsigned int b = c.i;
    return (unsigned short)((b + 0x7FFF + ((b >> 16) & 1)) >> 16);   // RNE
}

// count per (class, dst node); class = blockIdx&7 (XCD round-robin)
__global__ void k_bcnt(const int* __restrict__ dst, int* __restrict__ bcnt,
                       int E4, int E, int Nn) {
    int i = blockIdx.x * blockDim.x + threadIdx.x;
    const int base = (blockIdx.x & 7) * Nn;
    const int stride = gridDim.x * blockDim.x;
    for (; i < E4; i += stride) {
        const int4 d = ((const int4*)dst)[i];
        atomicAdd(&bcnt[base + d.x], 1);
        atomicAdd(&bcnt[base + d.y], 1);
        atomicAdd(&bcnt[base + d.z], 1);
        atomicAdd(&bcnt[base + d.w], 1);
    }
    // tail (E%4) handled by block 0 (class 0) -- must match k_bin's mapping
    if (blockIdx.x == 0) {
        const int t0 = E4 * 4;
        const int tl = E - t0;
        if ((int)threadIdx.x < tl) atomicAdd(&bcnt[dst[t0 + threadIdx.x]], 1);
    }
}

// dinv[i] = rsqrt(total degree + 1)
__global__ __launch_bounds__(256) void k_deg(const int* __restrict__ bcnt,
                                             float* __restrict__ dinv, int Nn) {
    const int i = blockIdx.x * 256 + threadIdx.x;
    if (i >= Nn) return;
    int d = 0;
#pragma unroll
    for (int c = 0; c < 8; ++c) d += bcnt[c * Nn + i];
    dinv[i] = rsqrtf((float)d + 1.0f);
}

// ---- flat hierarchical scan over bcnt[8N] ---------------------------------
// A: per-block (256 int4 = 1024 entries) sums -> partial
__global__ __launch_bounds__(256) void k_scanA(const int* __restrict__ bcnt,
                                               int* __restrict__ partial, int M4) {
    __shared__ int sm[256];
    const int t = threadIdx.x;
    const int i4 = blockIdx.x * 256 + t;
    int s = 0;
    if (i4 < M4) {
        const int4 v = ((const int4*)bcnt)[i4];
        s = (v.x + v.y) + (v.z + v.w);
    }
    sm[t] = s;
    __syncthreads();
    for (int off = 128; off > 0; off >>= 1) {
        if (t < off) sm[t] += sm[t + off];
        __syncthreads();
    }
    if (t == 0) partial[blockIdx.x] = sm[0];
}

// B: exclusive scan of block partials (NBLK <= 1024), in place
__global__ __launch_bounds__(1024) void k_scanB(int* __restrict__ partial, int NBLK) {
    __shared__ int sm[1024];
    const int t = threadIdx.x;
    const int v = (t < NBLK) ? partial[t] : 0;
    sm[t] = v;
    __syncthreads();
    for (int off = 1; off < 1024; off <<= 1) {
        const int u = (t >= off) ? sm[t - off] : 0;
        __syncthreads();
        sm[t] += u;
        __syncthreads();
    }
    if (t < NBLK) partial[t] = sm[t] - v;   // exclusive
}

// C: block-local prefix -> cur (claim bases), int4 per thread
__global__ __launch_bounds__(256) void k_scanC(const int* __restrict__ bcnt,
                                               const int* __restrict__ partial,
                                               int* __restrict__ cur, int M4) {
    __shared__ int sm[256];
    const int t = threadIdx.x;
    const int i4 = blockIdx.x * 256 + t;
    int4 v = make_int4(0, 0, 0, 0);
    if (i4 < M4) v = ((const int4*)bcnt)[i4];
    const int s = (v.x + v.y) + (v.z + v.w);
    sm[t] = s;
    __syncthreads();
    for (int off = 1; off < 256; off <<= 1) {
        const int u = (t >= off) ? sm[t - off] : 0;
        __syncthreads();
        sm[t] += u;
        __syncthreads();
    }
    if (i4 < M4) {
        int run = partial[blockIdx.x] + sm[t] - s;
        int4 w;
        w.x = run;
        w.y = w.x + v.x;
        w.z = w.y + v.y;
        w.w = w.z + v.z;
        ((int4*)cur)[i4] = w;
    }
}

// claim + write col[pos] = src. Same grid/mapping as k_bcnt.
__global__ void k_bin(const int* __restrict__ src, const int* __restrict__ dst,
                      int* __restrict__ cur, int* __restrict__ col,
                      int E4, int E, int Nn) {
    int i = blockIdx.x * blockDim.x + threadIdx.x;
    const int base = (blockIdx.x & 7) * Nn;
    const int stride = gridDim.x * blockDim.x;
    for (; i < E4; i += stride) {
        const int4 d = ((const int4*)dst)[i];
        const int4 sv = ((const int4*)src)[i];
        int p;
        p = atomicAdd(&cur[base + d.x], 1); col[p] = sv.x;
        p = atomicAdd(&cur[base + d.y], 1); col[p] = sv.y;
        p = atomicAdd(&cur[base + d.z], 1); col[p] = sv.z;
        p = atomicAdd(&cur[base + d.w], 1); col[p] = sv.w;
    }
    if (blockIdx.x == 0) {
        const int t0 = E4 * 4;
        const int tl = E - t0;
        if ((int)threadIdx.x < tl) {
            const int e = t0 + threadIdx.x;
            const int p = atomicAdd(&cur[dst[e]], 1);
            col[p] = src[e];
        }
    }
}

// Y[row] = bf16(dinv[row] * (X@W)[row]) ; X is f32 or bf16
template <int K, bool BF16IN>
__global__ __launch_bounds__(256) void k_mm(const void* __restrict__ Xv,
                                            const float* __restrict__ W,
                                            const float* __restrict__ dinv,
                                            unsigned short* __restrict__ Y, int n) {
    __shared__ float WL[K * 64];
    __shared__ float XT[32 * K];
    const int tid = threadIdx.x;
    for (int i = tid * 4; i < K * 64; i += 1024)
        *(float4*)&WL[i] = *(const float4*)&W[i];
    const int rowBase = blockIdx.x * 32;
    const int rows = min(32, n - rowBase);
    if (BF16IN) {
        const unsigned short* xs = (const unsigned short*)Xv + (size_t)rowBase * K;
        for (int i = tid * 4; i < rows * K; i += 1024) {
            const ushort4 u = *(const ushort4*)&xs[i];
            XT[i + 0] = bf2f(u.x); XT[i + 1] = bf2f(u.y);
            XT[i + 2] = bf2f(u.z); XT[i + 3] = bf2f(u.w);
        }
    } else {
        const float* xs = (const float*)Xv + (size_t)rowBase * K;
        for (int i = tid * 4; i < rows * K; i += 1024)
            *(float4*)&XT[i] = *(const float4*)&xs[i];
    }
    __syncthreads();
    const int colf = tid & 63;
    const int rg = tid >> 6;
    float acc[8] = {};
    for (int k4 = 0; k4 < K / 4; ++k4) {
        const float w0 = WL[(k4 * 4 + 0) * 64 + colf];
        const float w1 = WL[(k4 * 4 + 1) * 64 + colf];
        const float w2 = WL[(k4 * 4 + 2) * 64 + colf];
        const float w3 = WL[(k4 * 4 + 3) * 64 + colf];
#pragma unroll
        for (int r = 0; r < 8; ++r) {
            const float4 xv = *(const float4*)&XT[(rg * 8 + r) * K + k4 * 4];
            acc[r] += xv.x * w0 + xv.y * w1 + xv.z * w2 + xv.w * w3;
        }
    }
#pragma unroll
    for (int r = 0; r < 8; ++r) {
        const int row = rowBase + rg * 8 + r;
        if (row < n) Y[(size_t)row * 64 + colf] = f2bf(dinv[row] * acc[r]);
    }
}

// 8-segment CSR aggregation: wave per node, lane = feature.
// The 8 class segments are walked in lockstep -> up to 8 independent gathers
// in flight per iteration. cur[x] = segment end (post-bin), len = bcnt[x].
template <bool POOL>
__global__ __launch_bounds__(256) void k_agg(const int* __restrict__ col,
                                             const int* __restrict__ cur,
                                             const int* __restrict__ bcnt,
                                             const float* __restrict__ dinv,
                                             const unsigned short* __restrict__ XWs,
                                             const float* __restrict__ bias,
                                             unsigned short* __restrict__ Hout,
                                             const int* __restrict__ batch,
                                             float* __restrict__ emb,
                                             float* __restrict__ cnt, int Nn) {
    const int lane = threadIdx.x & 63;
    const int wid = (blockIdx.x * blockDim.x + threadIdx.x) >> 6;
    const int nw = (gridDim.x * blockDim.x) >> 6;
    const float bl = bias[lane];
    for (int i = wid; i < Nn; i += nw) {
        int sa[8], la[8];
        int mx = 0;
#pragma unroll
        for (int c = 0; c < 8; ++c) {
            const int e = cur[c * Nn + i];
            const int L = bcnt[c * Nn + i];
            sa[c] = e - L;
            la[c] = L;
            mx = max(mx, L);
        }
        float acc = 0.0f;
        for (int k = 0; k < mx; ++k) {
#pragma unroll
            for (int c = 0; c < 8; ++c) {
                if (k < la[c])
                    acc += bf2f(XWs[(size_t)col[sa[c] + k] * 64 + lane]);
            }
        }
        const float di = dinv[i];
        const float self = bf2f(XWs[(size_t)i * 64 + lane]);
        const float v = fmaxf(di * (acc + self) + bl, 0.0f);
        if (POOL) {
            const int g = batch[i];
            fatomic(&emb[(size_t)g * 64 + lane], v);
            if (lane == 0) fatomic(&cnt[g], 1.0f);
        } else {
            Hout[(size_t)i * 64 + lane] = f2bf(v);
        }
    }
}

// head: emb -> [e1,e2,|e1-e2|] @ fc1 -> relu -> @ fc2 -> sigmoid
__global__ __launch_bounds__(64) void k_head(const float* __restrict__ emb1, const float* __restrict__ cnt1,
                                             const float* __restrict__ emb2, const float* __restrict__ cnt2,
                                             const float* __restrict__ fc1W, const float* __restrict__ fc1b,
                                             const float* __restrict__ fc2W, const float* __restrict__ fc2b,
                                             float* __restrict__ out) {
    const int g = blockIdx.x;
    const int lane = threadIdx.x;
    __shared__ float comb[192];
    const float c1 = fmaxf(cnt1[g], 1.0f), c2 = fmaxf(cnt2[g], 1.0f);
    const float e1 = emb1[g * 64 + lane] / c1;
    const float e2 = emb2[g * 64 + lane] / c2;
    comb[lane] = e1;
    comb[64 + lane] = e2;
    comb[128 + lane] = fabsf(e1 - e2);
    __syncthreads();
    float acc = fc1b[lane];
    for (int k = 0; k < 192; ++k) acc += comb[k] * fc1W[k * 64 + lane];
    const float o1 = fmaxf(acc, 0.0f);
    float p = o1 * fc2W[lane];
#pragma unroll
    for (int off = 32; off > 0; off >>= 1) p += __shfl_xor(p, off);
    if (lane == 0) out[g] = 1.0f / (1.0f + expf(-(p + fc2b[0])));
}

extern "C" void kernel_launch(void* const* d_in, const int* in_sizes, int n_in,
                              void* d_out, int out_size, void* d_ws, size_t ws_size,
                              hipStream_t stream) {
    const float* x1   = (const float*)d_in[0];
    const int*   ei1  = (const int*)d_in[1];
    const int*   bt1  = (const int*)d_in[2];
    const float* x2   = (const float*)d_in[3];
    const int*   ei2  = (const int*)d_in[4];
    const int*   bt2  = (const int*)d_in[5];
    const float* W1   = (const float*)d_in[6];
    const float* bb1  = (const float*)d_in[7];
    const float* W2   = (const float*)d_in[8];
    const float* bb2  = (const float*)d_in[9];
    const float* fc1W = (const float*)d_in[10];
    const float* fc1b = (const float*)d_in[11];
    const float* fc2W = (const float*)d_in[12];
    const float* fc2b = (const float*)d_in[13];
    float* out = (float*)d_out;

    const int N = in_sizes[0] / 128;
    const int E = in_sizes[1] / 2;
    const int G = out_size;
    const int E4 = E / 4;
    const int M4 = (8 * N) / 4;                  // bcnt int4 count (8N % 4 == 0)
    const int NBLK = (M4 + 255) / 256;           // scan blocks (<= 1024)

    float* dinv   = (float*)d_ws;                    // N
    float* emb1   = dinv + N;                        // G*64
    float* cnt1   = emb1 + (size_t)G * 64;           // G
    float* emb2   = cnt1 + G;                        // G*64
    float* cnt2   = emb2 + (size_t)G * 64;           // G
    int* bcnt     = (int*)(cnt2 + G);                // N*8
    int* cur      = bcnt + (size_t)N * 8;            // N*8
    int* partial  = cur + (size_t)N * 8;             // 1024
    int* col      = partial + 1024;                  // E
    unsigned short* XWs = (unsigned short*)(col + E);      // N*64
    unsigned short* H1  = XWs + (size_t)N * 64;            // N*64

    const int mmGrid = (N + 31) / 32;

    for (int br = 0; br < 2; ++br) {
        const float* X = br ? x2 : x1;
        const int* ei  = br ? ei2 : ei1;
        const int* bt  = br ? bt2 : bt1;
        float* emb = br ? emb2 : emb1;
        float* cnt = br ? cnt2 : cnt1;
        const int* srcp = ei;
        const int* dstp = ei + E;

        hipMemsetAsync(bcnt, 0, (size_t)N * 8 * 4, stream);
        k_bcnt<<<2048, 256, 0, stream>>>(dstp, bcnt, E4, E, N);
        k_deg<<<(N + 255) / 256, 256, 0, stream>>>(bcnt, dinv, N);
        k_scanA<<<NBLK, 256, 0, stream>>>(bcnt, partial, M4);
        k_scanB<<<1, 1024, 0, stream>>>(partial, NBLK);
        k_scanC<<<NBLK, 256, 0, stream>>>(bcnt, partial, cur, M4);
        k_bin<<<2048, 256, 0, stream>>>(srcp, dstp, cur, col, E4, E, N);

        k_mm<128, false><<<mmGrid, 256, 0, stream>>>(X, W1, dinv, XWs, N);
        k_agg<false><<<2048, 256, 0, stream>>>(col, cur, bcnt, dinv, XWs, bb1,
                                               H1, nullptr, nullptr, nullptr, N);
        k_mm<64, true><<<mmGrid, 256, 0, stream>>>(H1, W2, dinv, XWs, N);
        hipMemsetAsync(emb, 0, (size_t)(G * 64 + G) * 4, stream);
        k_agg<true><<<2048, 256, 0, stream>>>(col, cur, bcnt, dinv, XWs, bb2,
                                              nullptr, bt, emb, cnt, N);
    }
    k_head<<<G, 64, 0, stream>>>(emb1, cnt1, emb2, cnt2, fc1W, fc1b, fc2W, fc2b, out);
}

// Round 7
// 1440.480 us; speedup vs baseline: 1.4421x; 1.4421x over previous
//
#include <hip/hip_runtime.h>
#include <cstdint>

// ---------------------------------------------------------------------------
// GCN Siamese. Class-major binning (XCD-private write lines) -> reorder to
// node-major CSR -> contiguous unroll-16 gather aggregation.
//   per branch:
//     k_bcnt : count per (class=blockIdx&7, dst)  [bcnt[c*N+d]]
//     k_deg  : degN, dinv, rowstart[N]=E
//     scanA/B/C (bcnt[8N])  -> cur   (class-major claim bases)
//     scanA/B/C (degN[N])   -> rowstart (node-major CSR)
//     k_bin  : class-major claim+write col        (after: cur = segment ends)
//     k_reorder: col (class-major) -> colN (node-major rows)
//     k_mm<128>: XWs = bf16(dinv * (X@W1))
//     k_agg<false>: wave/node, unroll-16 gather; H1 = bf16(relu(...))
//     k_mm<64> : XWs = bf16(dinv * (H1@W2))
//     k_agg<true>: same, epilogue pools into emb/cnt
//   head: sigmoid(relu([e1,e2,|e1-e2|]@fc1+b)@fc2+b)
// N=100000, E=3.2M, G=1024
// ---------------------------------------------------------------------------

__device__ __forceinline__ float fatomic(float* p, float v) {
    return unsafeAtomicAdd(p, v);   // hw global_atomic_add_f32
}
__device__ __forceinline__ float bf2f(unsigned short u) {
    union { unsigned int i; float f; } c; c.i = ((unsigned int)u) << 16; return c.f;
}
__device__ __forceinline__ unsigned short f2bf(float f) {
    union { float f; unsigned int i; } c; c.f = f;
    const unsigned int b = c.i;
    return (unsigned short)((b + 0x7FFF + ((b >> 16) & 1)) >> 16);   // RNE
}

// count per (class, dst node); class = blockIdx&7 (XCD round-robin)
__global__ void k_bcnt(const int* __restrict__ dst, int* __restrict__ bcnt,
                       int E4, int E, int Nn) {
    int i = blockIdx.x * blockDim.x + threadIdx.x;
    const int base = (blockIdx.x & 7) * Nn;
    const int stride = gridDim.x * blockDim.x;
    for (; i < E4; i += stride) {
        const int4 d = ((const int4*)dst)[i];
        atomicAdd(&bcnt[base + d.x], 1);
        atomicAdd(&bcnt[base + d.y], 1);
        atomicAdd(&bcnt[base + d.z], 1);
        atomicAdd(&bcnt[base + d.w], 1);
    }
    if (blockIdx.x == 0) {       // tail, class 0 (must match k_bin)
        const int t0 = E4 * 4;
        const int tl = E - t0;
        if ((int)threadIdx.x < tl) atomicAdd(&bcnt[dst[t0 + threadIdx.x]], 1);
    }
}

// degN[i], dinv[i]; rowstart[N] = E
__global__ __launch_bounds__(256) void k_deg(const int* __restrict__ bcnt,
                                             int* __restrict__ degN,
                                             float* __restrict__ dinv,
                                             int* __restrict__ rowstart,
                                             int Nn, int E) {
    const int i = blockIdx.x * 256 + threadIdx.x;
    if (i == 0) rowstart[Nn] = E;
    if (i >= Nn) return;
    int d = 0;
#pragma unroll
    for (int c = 0; c < 8; ++c) d += bcnt[c * Nn + i];
    degN[i] = d;
    dinv[i] = rsqrtf((float)d + 1.0f);
}

// ---- generic flat hierarchical exclusive scan (M ints, M%4==0) ------------
__global__ __launch_bounds__(256) void k_scanA(const int* __restrict__ in,
                                               int* __restrict__ partial, int M4) {
    __shared__ int sm[256];
    const int t = threadIdx.x;
    const int i4 = blockIdx.x * 256 + t;
    int s = 0;
    if (i4 < M4) {
        const int4 v = ((const int4*)in)[i4];
        s = (v.x + v.y) + (v.z + v.w);
    }
    sm[t] = s;
    __syncthreads();
    for (int off = 128; off > 0; off >>= 1) {
        if (t < off) sm[t] += sm[t + off];
        __syncthreads();
    }
    if (t == 0) partial[blockIdx.x] = sm[0];
}

__global__ __launch_bounds__(1024) void k_scanB(int* __restrict__ partial, int NBLK) {
    __shared__ int sm[1024];
    const int t = threadIdx.x;
    const int v = (t < NBLK) ? partial[t] : 0;
    sm[t] = v;
    __syncthreads();
    for (int off = 1; off < 1024; off <<= 1) {
        const int u = (t >= off) ? sm[t - off] : 0;
        __syncthreads();
        sm[t] += u;
        __syncthreads();
    }
    if (t < NBLK) partial[t] = sm[t] - v;   // exclusive
}

__global__ __launch_bounds__(256) void k_scanC(const int* __restrict__ in,
                                               const int* __restrict__ partial,
                                               int* __restrict__ outbase, int M4) {
    __shared__ int sm[256];
    const int t = threadIdx.x;
    const int i4 = blockIdx.x * 256 + t;
    int4 v = make_int4(0, 0, 0, 0);
    if (i4 < M4) v = ((const int4*)in)[i4];
    const int s = (v.x + v.y) + (v.z + v.w);
    sm[t] = s;
    __syncthreads();
    for (int off = 1; off < 256; off <<= 1) {
        const int u = (t >= off) ? sm[t - off] : 0;
        __syncthreads();
        sm[t] += u;
        __syncthreads();
    }
    if (i4 < M4) {
        int run = partial[blockIdx.x] + sm[t] - s;
        int4 w;
        w.x = run;
        w.y = w.x + v.x;
        w.z = w.y + v.y;
        w.w = w.z + v.z;
        ((int4*)outbase)[i4] = w;
    }
}

// claim + write col[pos] = src (class-major). Same mapping as k_bcnt.
__global__ void k_bin(const int* __restrict__ src, const int* __restrict__ dst,
                      int* __restrict__ cur, int* __restrict__ col,
                      int E4, int E, int Nn) {
    int i = blockIdx.x * blockDim.x + threadIdx.x;
    const int base = (blockIdx.x & 7) * Nn;
    const int stride = gridDim.x * blockDim.x;
    for (; i < E4; i += stride) {
        const int4 d = ((const int4*)dst)[i];
        const int4 sv = ((const int4*)src)[i];
        int p;
        p = atomicAdd(&cur[base + d.x], 1); col[p] = sv.x;
        p = atomicAdd(&cur[base + d.y], 1); col[p] = sv.y;
        p = atomicAdd(&cur[base + d.z], 1); col[p] = sv.z;
        p = atomicAdd(&cur[base + d.w], 1); col[p] = sv.w;
    }
    if (blockIdx.x == 0) {
        const int t0 = E4 * 4;
        const int tl = E - t0;
        if ((int)threadIdx.x < tl) {
            const int e = t0 + threadIdx.x;
            const int p = atomicAdd(&cur[dst[e]], 1);
            col[p] = src[e];
        }
    }
}

// class-major col -> node-major colN. Thread = (node i = tid>>3, class c = tid&7).
// 8-lane shfl prefix gives within-row offset; 8 adjacent lanes complete one
// node's contiguous output row -> dense coalesced writes.
__global__ __launch_bounds__(256) void k_reorder(const int* __restrict__ col,
                                                 const int* __restrict__ cur,
                                                 const int* __restrict__ bcnt,
                                                 const int* __restrict__ rowstart,
                                                 int* __restrict__ colN, int Nn) {
    const int tid = blockIdx.x * 256 + threadIdx.x;
    if (tid >= Nn * 8) return;
    const int i = tid >> 3;
    const int c = tid & 7;
    const int L = bcnt[c * Nn + i];
    // exclusive prefix of L over the 8-lane group (same node)
    int pref = L;
#pragma unroll
    for (int d = 1; d < 8; d <<= 1) {
        const int u = __shfl_up(pref, d, 8);
        if (c >= d) pref += u;
    }
    const int off = rowstart[i] + (pref - L);
    if (L == 0) return;
    const int s0 = cur[c * Nn + i] - L;     // class-major segment start
    for (int k = 0; k < L; ++k)
        colN[off + k] = col[s0 + k];
}

// Y[row] = bf16(dinv[row] * (X@W)[row]) ; X is f32 or bf16
template <int K, bool BF16IN>
__global__ __launch_bounds__(256) void k_mm(const void* __restrict__ Xv,
                                            const float* __restrict__ W,
                                            const float* __restrict__ dinv,
                                            unsigned short* __restrict__ Y, int n) {
    __shared__ float WL[K * 64];
    __shared__ float XT[32 * K];
    const int tid = threadIdx.x;
    for (int i = tid * 4; i < K * 64; i += 1024)
        *(float4*)&WL[i] = *(const float4*)&W[i];
    const int rowBase = blockIdx.x * 32;
    const int rows = min(32, n - rowBase);
    if (BF16IN) {
        const unsigned short* xs = (const unsigned short*)Xv + (size_t)rowBase * K;
        for (int i = tid * 4; i < rows * K; i += 1024) {
            const ushort4 u = *(const ushort4*)&xs[i];
            XT[i + 0] = bf2f(u.x); XT[i + 1] = bf2f(u.y);
            XT[i + 2] = bf2f(u.z); XT[i + 3] = bf2f(u.w);
        }
    } else {
        const float* xs = (const float*)Xv + (size_t)rowBase * K;
        for (int i = tid * 4; i < rows * K; i += 1024)
            *(float4*)&XT[i] = *(const float4*)&xs[i];
    }
    __syncthreads();
    const int colf = tid & 63;
    const int rg = tid >> 6;
    float acc[8] = {};
    for (int k4 = 0; k4 < K / 4; ++k4) {
        const float w0 = WL[(k4 * 4 + 0) * 64 + colf];
        const float w1 = WL[(k4 * 4 + 1) * 64 + colf];
        const float w2 = WL[(k4 * 4 + 2) * 64 + colf];
        const float w3 = WL[(k4 * 4 + 3) * 64 + colf];
#pragma unroll
        for (int r = 0; r < 8; ++r) {
            const float4 xv = *(const float4*)&XT[(rg * 8 + r) * K + k4 * 4];
            acc[r] += xv.x * w0 + xv.y * w1 + xv.z * w2 + xv.w * w3;
        }
    }
#pragma unroll
    for (int r = 0; r < 8; ++r) {
        const int row = rowBase + rg * 8 + r;
        if (row < n) Y[(size_t)row * 64 + colf] = f2bf(dinv[row] * acc[r]);
    }
}

// node-major CSR aggregation: wave per node, lane = feature, unroll-16.
template <bool POOL>
__global__ __launch_bounds__(256) void k_agg(const int* __restrict__ colN,
                                             const int* __restrict__ rowstart,
                                             const float* __restrict__ dinv,
                                             const unsigned short* __restrict__ XWs,
                                             const float* __restrict__ bias,
                                             unsigned short* __restrict__ Hout,
                                             const int* __restrict__ batch,
                                             float* __restrict__ emb,
                                             float* __restrict__ cnt, int Nn) {
    const int lane = threadIdx.x & 63;
    const int wid = (blockIdx.x * blockDim.x + threadIdx.x) >> 6;
    const int nw = (gridDim.x * blockDim.x) >> 6;
    const float bl = bias[lane];
    for (int i = wid; i < Nn; i += nw) {
        const int s = rowstart[i], e = rowstart[i + 1];
        float acc = 0.0f;
        int j = s;
        for (; j + 16 <= e; j += 16) {
            float a[16];
#pragma unroll
            for (int q = 0; q < 16; ++q)
                a[q] = bf2f(XWs[(size_t)colN[j + q] * 64 + lane]);
            float t0 = ((a[0] + a[1]) + (a[2] + a[3])) + ((a[4] + a[5]) + (a[6] + a[7]));
            float t1 = ((a[8] + a[9]) + (a[10] + a[11])) + ((a[12] + a[13]) + (a[14] + a[15]));
            acc += t0 + t1;
        }
        for (; j + 4 <= e; j += 4) {
            const float a0 = bf2f(XWs[(size_t)colN[j + 0] * 64 + lane]);
            const float a1 = bf2f(XWs[(size_t)colN[j + 1] * 64 + lane]);
            const float a2 = bf2f(XWs[(size_t)colN[j + 2] * 64 + lane]);
            const float a3 = bf2f(XWs[(size_t)colN[j + 3] * 64 + lane]);
            acc += (a0 + a1) + (a2 + a3);
        }
        for (; j < e; ++j)
            acc += bf2f(XWs[(size_t)colN[j] * 64 + lane]);
        const float di = dinv[i];
        const float self = bf2f(XWs[(size_t)i * 64 + lane]);
        const float v = fmaxf(di * (acc + self) + bl, 0.0f);
        if (POOL) {
            const int g = batch[i];
            fatomic(&emb[(size_t)g * 64 + lane], v);
            if (lane == 0) fatomic(&cnt[g], 1.0f);
        } else {
            Hout[(size_t)i * 64 + lane] = f2bf(v);
        }
    }
}

// head: emb -> [e1,e2,|e1-e2|] @ fc1 -> relu -> @ fc2 -> sigmoid
__global__ __launch_bounds__(64) void k_head(const float* __restrict__ emb1, const float* __restrict__ cnt1,
                                             const float* __restrict__ emb2, const float* __restrict__ cnt2,
                                             const float* __restrict__ fc1W, const float* __restrict__ fc1b,
                                             const float* __restrict__ fc2W, const float* __restrict__ fc2b,
                                             float* __restrict__ out) {
    const int g = blockIdx.x;
    const int lane = threadIdx.x;
    __shared__ float comb[192];
    const float c1 = fmaxf(cnt1[g], 1.0f), c2 = fmaxf(cnt2[g], 1.0f);
    const float e1 = emb1[g * 64 + lane] / c1;
    const float e2 = emb2[g * 64 + lane] / c2;
    comb[lane] = e1;
    comb[64 + lane] = e2;
    comb[128 + lane] = fabsf(e1 - e2);
    __syncthreads();
    float acc = fc1b[lane];
    for (int k = 0; k < 192; ++k) acc += comb[k] * fc1W[k * 64 + lane];
    const float o1 = fmaxf(acc, 0.0f);
    float p = o1 * fc2W[lane];
#pragma unroll
    for (int off = 32; off > 0; off >>= 1) p += __shfl_xor(p, off);
    if (lane == 0) out[g] = 1.0f / (1.0f + expf(-(p + fc2b[0])));
}

extern "C" void kernel_launch(void* const* d_in, const int* in_sizes, int n_in,
                              void* d_out, int out_size, void* d_ws, size_t ws_size,
                              hipStream_t stream) {
    const float* x1   = (const float*)d_in[0];
    const int*   ei1  = (const int*)d_in[1];
    const int*   bt1  = (const int*)d_in[2];
    const float* x2   = (const float*)d_in[3];
    const int*   ei2  = (const int*)d_in[4];
    const int*   bt2  = (const int*)d_in[5];
    const float* W1   = (const float*)d_in[6];
    const float* bb1  = (const float*)d_in[7];
    const float* W2   = (const float*)d_in[8];
    const float* bb2  = (const float*)d_in[9];
    const float* fc1W = (const float*)d_in[10];
    const float* fc1b = (const float*)d_in[11];
    const float* fc2W = (const float*)d_in[12];
    const float* fc2b = (const float*)d_in[13];
    float* out = (float*)d_out;

    const int N = in_sizes[0] / 128;
    const int E = in_sizes[1] / 2;
    const int G = out_size;
    const int E4 = E / 4;
    const int M4b = (8 * N) / 4;                 // bcnt scan (ints/4)
    const int NBLKb = (M4b + 255) / 256;
    const int M4d = N / 4;                       // degN scan (N % 4 == 0)
    const int NBLKd = (M4d + 255) / 256;

    float* dinv   = (float*)d_ws;                    // N
    float* emb1   = dinv + N;                        // G*64
    float* cnt1   = emb1 + (size_t)G * 64;           // G
    float* emb2   = cnt1 + G;                        // G*64
    float* cnt2   = emb2 + (size_t)G * 64;           // G
    int* degN     = (int*)(cnt2 + G);                // N
    int* rowstart = degN + N;                        // N+1
    int* bcnt     = rowstart + (N + 1);              // 8N
    int* cur      = bcnt + (size_t)N * 8;            // 8N
    int* partial  = cur + (size_t)N * 8;             // 1024
    int* col      = partial + 1024;                  // E  (class-major; H1 overlays)
    int* colN     = col + E;                         // E  (node-major)
    unsigned short* XWs = (unsigned short*)(colN + E);     // N*64
    unsigned short* H1  = (unsigned short*)col;            // overlay (col dead post-reorder)

    const int mmGrid = (N + 31) / 32;

    for (int br = 0; br < 2; ++br) {
        const float* X = br ? x2 : x1;
        const int* ei  = br ? ei2 : ei1;
        const int* bt  = br ? bt2 : bt1;
        float* emb = br ? emb2 : emb1;
        float* cnt = br ? cnt2 : cnt1;
        const int* srcp = ei;
        const int* dstp = ei + E;

        hipMemsetAsync(bcnt, 0, (size_t)N * 8 * 4, stream);
        k_bcnt<<<2048, 256, 0, stream>>>(dstp, bcnt, E4, E, N);
        k_deg<<<(N + 255) / 256, 256, 0, stream>>>(bcnt, degN, dinv, rowstart, N, E);
        k_scanA<<<NBLKb, 256, 0, stream>>>(bcnt, partial, M4b);
        k_scanB<<<1, 1024, 0, stream>>>(partial, NBLKb);
        k_scanC<<<NBLKb, 256, 0, stream>>>(bcnt, partial, cur, M4b);
        k_scanA<<<NBLKd, 256, 0, stream>>>(degN, partial, M4d);
        k_scanB<<<1, 1024, 0, stream>>>(partial, NBLKd);
        k_scanC<<<NBLKd, 256, 0, stream>>>(degN, partial, rowstart, M4d);
        k_bin<<<2048, 256, 0, stream>>>(srcp, dstp, cur, col, E4, E, N);
        k_reorder<<<(N * 8 + 255) / 256, 256, 0, stream>>>(col, cur, bcnt, rowstart, colN, N);

        k_mm<128, false><<<mmGrid, 256, 0, stream>>>(X, W1, dinv, XWs, N);
        k_agg<false><<<2048, 256, 0, stream>>>(colN, rowstart, dinv, XWs, bb1,
                                               H1, nullptr, nullptr, nullptr, N);
        k_mm<64, true><<<mmGrid, 256, 0, stream>>>(H1, W2, dinv, XWs, N);
        hipMemsetAsync(emb, 0, (size_t)(G * 64 + G) * 4, stream);
        k_agg<true><<<2048, 256, 0, stream>>>(colN, rowstart, dinv, XWs, bb2,
                                              nullptr, bt, emb, cnt, N);
    }
    k_head<<<G, 64, 0, stream>>>(emb1, cnt1, emb2, cnt2, fc1W, fc1b, fc2W, fc2b, out);
}